// Round 13
// baseline (51.002 us; speedup 1.0000x reference)
//
#include <hip/hip_runtime.h>

#define DIMS 64
#define KCB 512
#define OUT_Q 8388608   // 32*64*64*64
#define MAIN_WGS 1024

typedef float f32x4 __attribute__((ext_vector_type(4)));
typedef float f4    __attribute__((ext_vector_type(4)));

// ws layout (bytes):
//   [0..4096)     float per-WG partial loss sums [1024]
//   [4096..6144)  float scaled norms: -128*||c_k||^2  (= -0.5*||256c||^2/256)
//   [8192..40960) fp8 e4m3(256*cb) packed in MFMA B-fragment order:
//                 byte = 8192 + kt*1024 + h*512 + l*8 + i
//                 holds fp8(256*cb[kt*16+(l&15)][h*32+((l>>4)&3)*8 + i])

static __device__ __forceinline__ unsigned int f2fp8(float f) {
    // fp32 -> OCP e4m3fn, RNE, subnormal-correct. Used only in prep (cold).
    unsigned int u = __float_as_uint(f);
    unsigned int sign = (u >> 24) & 0x80u;
    if ((u & 0x7FFFFFFFu) == 0) return sign;
    int exp = (int)((u >> 23) & 0xFFu) - 127;
    unsigned int m24 = (u & 0x7FFFFFu) | 0x800000u;
    if (exp >= -6) {
        unsigned int keep = m24 >> 20;
        unsigned int rem = m24 & 0xFFFFFu;
        if (rem > 0x80000u || (rem == 0x80000u && (keep & 1u))) keep++;
        if (keep >= 16u) { keep >>= 1; exp++; }
        int e = exp + 7;
        if (e >= 16) return sign | 0x7Eu;                       // clamp 448
        if (e == 15 && (keep & 7u) == 7u) return sign | 0x7Eu;  // avoid NaN
        return sign | ((unsigned)e << 3) | (keep & 7u);
    } else {
        int sh = 14 - exp;                   // >= 21
        if (sh > 31) return sign;            // underflow
        unsigned int keep = m24 >> sh;
        unsigned int rem = m24 & ((1u << sh) - 1u);
        unsigned int half = 1u << (sh - 1);
        if (rem > half || (rem == half && (keep & 1u))) keep++;
        if (keep >= 8u) return sign | 0x08u; // rounds up to min normal
        return sign | keep;
    }
}

__global__ void vq_prep(const float* __restrict__ cb, float* __restrict__ ws) {
    int t = blockIdx.x * blockDim.x + threadIdx.x;   // 0..4607
    if (t < 4096) {
        // pack one 8-byte fp8 B-fragment slice
        int kt = t >> 7, rest = t & 127;
        int h = rest >> 6, l = rest & 63;
        int row = kt * 16 + (l & 15);
        int col = h * 32 + ((l >> 4) & 3) * 8;
        const f4* p = (const f4*)(cb + row * DIMS + col);
        f4 u0 = p[0], u1 = p[1];
        unsigned int lo = f2fp8(256.0f * u0[0])
                        | (f2fp8(256.0f * u0[1]) << 8)
                        | (f2fp8(256.0f * u0[2]) << 16)
                        | (f2fp8(256.0f * u0[3]) << 24);
        unsigned int hi = f2fp8(256.0f * u1[0])
                        | (f2fp8(256.0f * u1[1]) << 8)
                        | (f2fp8(256.0f * u1[2]) << 16)
                        | (f2fp8(256.0f * u1[3]) << 24);
        unsigned int* dst = (unsigned int*)((char*)ws + 8192 + kt * 1024 + h * 512 + l * 8);
        dst[0] = lo;
        dst[1] = hi;
    } else if (t < 4096 + KCB) {
        int r = t - 4096;
        const f4* p = (const f4*)(cb + r * DIMS);
        float s = 0.0f;
#pragma unroll
        for (int i = 0; i < DIMS / 4; ++i) {
            f4 v = p[i];
            s += v[0]*v[0] + v[1]*v[1] + v[2]*v[2] + v[3]*v[3];
        }
        ((float*)((char*)ws + 4096))[r] = -128.0f * s;
    }
}

__global__ __launch_bounds__(512, 8) void vq_main(const float* __restrict__ x,
                                                  const float* __restrict__ cb,
                                                  float* __restrict__ out,
                                                  float* __restrict__ ws) {
    __shared__ char lds[34816];   // 32 KiB fp8 codebook + 2 KiB norms

    const int tid  = threadIdx.x;
    const int lane = tid & 63;
    const int wid  = tid >> 6;
    const long rowbase = ((long)blockIdx.x * 8 + wid) * 16;  // 16 rows per wave
    const int r15 = lane & 15;
    const int g   = lane >> 4;

    // ---- stage fp8 codebook (32 KiB) + norms (2 KiB) into LDS (linear, coalesced)
    {
        const f4* src = (const f4*)((const char*)ws + 8192);
        f4 s0 = src[tid];
        f4 s1 = src[512 + tid];
        f4 s2 = src[1024 + tid];
        f4 s3 = src[1536 + tid];
        float nv = ((const float*)((const char*)ws + 4096))[tid];
        f4* dst = (f4*)lds;
        dst[tid]        = s0;
        dst[512 + tid]  = s1;
        dst[1024 + tid] = s2;
        dst[1536 + tid] = s3;
        ((float*)(lds + 32768))[tid] = nv;
    }

    // ---- x row (16 rows/wave): load 16 floats/lane, fp8 A-frags + fp32 norm
    unsigned long A0, A1;
    float xn0;
    {
        const float* xa = x + (rowbase + r15) * DIMS + g * 8;
        f4 a0 = *(const f4*)(xa);
        f4 a1 = *(const f4*)(xa + 4);
        f4 a2 = *(const f4*)(xa + 32);
        f4 a3 = *(const f4*)(xa + 36);
        xn0 = a0[0]*a0[0]+a0[1]*a0[1]+a0[2]*a0[2]+a0[3]*a0[3]
            + a1[0]*a1[0]+a1[1]*a1[1]+a1[2]*a1[2]+a1[3]*a1[3]
            + a2[0]*a2[0]+a2[1]*a2[1]+a2[2]*a2[2]+a2[3]*a2[3]
            + a3[0]*a3[0]+a3[1]*a3[1]+a3[2]*a3[2]+a3[3]*a3[3];
        unsigned int t0, t1, t2, t3, t4, t5, t6, t7;
        asm("v_cvt_pk_fp8_f32 %0, %1, %2" : "=v"(t0) : "v"(a0[0]), "v"(a0[1]));
        asm("v_cvt_pk_fp8_f32 %0, %1, %2" : "=v"(t1) : "v"(a0[2]), "v"(a0[3]));
        asm("v_cvt_pk_fp8_f32 %0, %1, %2" : "=v"(t2) : "v"(a1[0]), "v"(a1[1]));
        asm("v_cvt_pk_fp8_f32 %0, %1, %2" : "=v"(t3) : "v"(a1[2]), "v"(a1[3]));
        asm("v_cvt_pk_fp8_f32 %0, %1, %2" : "=v"(t4) : "v"(a2[0]), "v"(a2[1]));
        asm("v_cvt_pk_fp8_f32 %0, %1, %2" : "=v"(t5) : "v"(a2[2]), "v"(a2[3]));
        asm("v_cvt_pk_fp8_f32 %0, %1, %2" : "=v"(t6) : "v"(a3[0]), "v"(a3[1]));
        asm("v_cvt_pk_fp8_f32 %0, %1, %2" : "=v"(t7) : "v"(a3[2]), "v"(a3[3]));
        unsigned int dw0 = (t0 & 0xFFFFu) | (t1 << 16);
        unsigned int dw1 = (t2 & 0xFFFFu) | (t3 << 16);
        unsigned int dw2 = (t4 & 0xFFFFu) | (t5 << 16);
        unsigned int dw3 = (t6 & 0xFFFFu) | (t7 << 16);
        A0 = (unsigned long)dw0 | ((unsigned long)dw1 << 32);
        A1 = (unsigned long)dw2 | ((unsigned long)dw3 << 32);
    }
    // full row norm: fold the 4 g-groups (lane keeps ||x_row(r15)||^2)
    xn0 += __shfl_xor(xn0, 16, 64);
    xn0 += __shfl_xor(xn0, 32, 64);

    __syncthreads();   // LDS codebook + norms ready

    // ---- mantissa-packed argmax state (low 9 bits of score carry k)
    float bv0 = -3.4e38f, bv1 = -3.4e38f, bv2 = -3.4e38f, bv3 = -3.4e38f;

    const char*  ldsb = lds;
    const float* ldsn = (const float*)(lds + 32768);
    const int laneoff = lane * 8;

#pragma unroll
    for (int kt = 0; kt < 32; ++kt) {
        unsigned long b0 = *(const unsigned long*)(ldsb + kt * 1024 + laneoff);
        unsigned long b1 = *(const unsigned long*)(ldsb + kt * 1024 + 512 + laneoff);
        float ic = ldsn[kt * 16 + r15];          // conflict-free broadcast read
        f32x4 init = {ic, ic, ic, ic};
        f32x4 q = __builtin_amdgcn_mfma_f32_16x16x32_fp8_fp8((long)A0, (long)b0, init, 0, 0, 0);
        q       = __builtin_amdgcn_mfma_f32_16x16x32_fp8_fp8((long)A1, (long)b1, q,    0, 0, 0);
        const unsigned int kr = (unsigned int)(kt * 16 + r15);
        bv0 = fmaxf(bv0, __uint_as_float((__float_as_uint(q[0]) & 0xFFFFFE00u) | kr));
        bv1 = fmaxf(bv1, __uint_as_float((__float_as_uint(q[1]) & 0xFFFFFE00u) | kr));
        bv2 = fmaxf(bv2, __uint_as_float((__float_as_uint(q[2]) & 0xFFFFFE00u) | kr));
        bv3 = fmaxf(bv3, __uint_as_float((__float_as_uint(q[3]) & 0xFFFFFE00u) | kr));
    }

    // ---- argmax reduce across the 16 entry-lanes of each row-group
#pragma unroll
    for (int st = 0; st < 4; ++st) {
        const int m = 1 << st;
        bv0 = fmaxf(bv0, __shfl_xor(bv0, m, 64));
        bv1 = fmaxf(bv1, __shfl_xor(bv1, m, 64));
        bv2 = fmaxf(bv2, __shfl_xor(bv2, m, 64));
        bv3 = fmaxf(bv3, __shfl_xor(bv3, m, 64));
    }

    // ---- epilogue: pure gather -> store (no x re-read)
    {
        const int orow = lane >> 2;        // 0..15; orow>>2 == g always
        const int cseg = lane & 3;
        const int j2   = orow & 3;
        const int idx = (int)(__float_as_uint(j2 == 0 ? bv0 : j2 == 1 ? bv1 :
                                              j2 == 2 ? bv2 : bv3) & 511u);
        const f4* cq = (const f4*)(cb + (long)idx * DIMS + cseg * 16);
        f4* op = (f4*)(out + (rowbase + orow) * DIMS + cseg * 16);
        op[0] = cq[0]; op[1] = cq[1]; op[2] = cq[2]; op[3] = cq[3];
    }

    // ---- loss from scores: ||q-x||^2 = ||x||^2 - 2*(s'/256) = xn - s'/128
    float lsum = 0.0f;
    if (g == (r15 >> 2)) {                 // one lane per row r15
        const int jp = r15 & 3;
        float s0 = jp == 0 ? bv0 : jp == 1 ? bv1 : jp == 2 ? bv2 : bv3;
        s0 = __uint_as_float(__float_as_uint(s0) & 0xFFFFFE00u);
        lsum = xn0 - s0 * 0.0078125f;
    }
#pragma unroll
    for (int s = 0; s < 6; ++s) lsum += __shfl_xor(lsum, 1 << s, 64);

    __syncthreads();                       // all waves done reading lds codebook
    float* lsred = (float*)lds;
    if (lane == 0) lsred[wid] = lsum;
    __syncthreads();
    if (tid == 0) {
        ws[blockIdx.x] = lsred[0] + lsred[1] + lsred[2] + lsred[3]
                       + lsred[4] + lsred[5] + lsred[6] + lsred[7];
    }
}

__global__ __launch_bounds__(256) void vq_final(const float* __restrict__ ws,
                                                float* __restrict__ out) {
    const int t = threadIdx.x;
    float s = ws[t] + ws[t + 256] + ws[t + 512] + ws[t + 768];
#pragma unroll
    for (int st = 0; st < 6; ++st) s += __shfl_xor(s, 1 << st, 64);
    __shared__ float w2[4];
    if ((t & 63) == 0) w2[t >> 6] = s;
    __syncthreads();
    if (t == 0) {
        float total = w2[0] + w2[1] + w2[2] + w2[3];
        out[OUT_Q] = 1.25f * total / 8388608.0f;
    }
}

extern "C" void kernel_launch(void* const* d_in, const int* in_sizes, int n_in,
                              void* d_out, int out_size, void* d_ws, size_t ws_size,
                              hipStream_t stream) {
    const float* x  = (const float*)d_in[0];
    const float* cb = (const float*)d_in[1];
    float* out = (float*)d_out;
    float* ws  = (float*)d_ws;
    vq_prep<<<18, 256, 0, stream>>>(cb, ws);
    // MEASUREMENT ROUND: vq_main is idempotent (pure function of inputs ->
    // identical out/ws values every call), so a second launch is graph-safe
    // and isolates vq_main's marginal wall time: main = total_R13 - total_R11.
    vq_main<<<MAIN_WGS, 512, 0, stream>>>(x, cb, out, ws);
    vq_main<<<MAIN_WGS, 512, 0, stream>>>(x, cb, out, ws);
    vq_final<<<1, 256, 0, stream>>>(ws, out);
}

// Round 14
// 32.124 us; speedup vs baseline: 1.5877x; 1.5877x over previous
//
#include <hip/hip_runtime.h>

#define DIMS 64
#define KCB 512
#define OUT_Q 8388608   // 32*64*64*64
#define MAIN_WGS 1024

typedef float f32x4 __attribute__((ext_vector_type(4)));
typedef float f4    __attribute__((ext_vector_type(4)));

// ws layout (bytes):
//   [0..32768)      fp8 e4m3(256*cb) packed in MFMA B-fragment order:
//                   byte = kt*1024 + h*512 + l*8 + i
//                   holds fp8(256*cb[kt*16+(l&15)][h*32+((l>>4)&3)*8 + i])
//   [32768..34816)  float scaled norms: -128*||c_k||^2
//   [34816..67584)  float per-WAVE partial loss sums [8192]

static __device__ __forceinline__ unsigned int f2fp8(float f) {
    // fp32 -> OCP e4m3fn, RNE, subnormal-correct. Used only in prep (cold).
    unsigned int u = __float_as_uint(f);
    unsigned int sign = (u >> 24) & 0x80u;
    if ((u & 0x7FFFFFFFu) == 0) return sign;
    int exp = (int)((u >> 23) & 0xFFu) - 127;
    unsigned int m24 = (u & 0x7FFFFFu) | 0x800000u;
    if (exp >= -6) {
        unsigned int keep = m24 >> 20;
        unsigned int rem = m24 & 0xFFFFFu;
        if (rem > 0x80000u || (rem == 0x80000u && (keep & 1u))) keep++;
        if (keep >= 16u) { keep >>= 1; exp++; }
        int e = exp + 7;
        if (e >= 16) return sign | 0x7Eu;                       // clamp 448
        if (e == 15 && (keep & 7u) == 7u) return sign | 0x7Eu;  // avoid NaN
        return sign | ((unsigned)e << 3) | (keep & 7u);
    } else {
        int sh = 14 - exp;                   // >= 21
        if (sh > 31) return sign;            // underflow
        unsigned int keep = m24 >> sh;
        unsigned int rem = m24 & ((1u << sh) - 1u);
        unsigned int half = 1u << (sh - 1);
        if (rem > half || (rem == half && (keep & 1u))) keep++;
        if (keep >= 8u) return sign | 0x08u; // rounds up to min normal
        return sign | keep;
    }
}

__global__ void vq_prep(const float* __restrict__ cb, float* __restrict__ ws) {
    int t = blockIdx.x * blockDim.x + threadIdx.x;   // 0..4607
    if (t < 4096) {
        // pack one 8-byte fp8 B-fragment slice
        int kt = t >> 7, rest = t & 127;
        int h = rest >> 6, l = rest & 63;
        int row = kt * 16 + (l & 15);
        int col = h * 32 + ((l >> 4) & 3) * 8;
        const f4* p = (const f4*)(cb + row * DIMS + col);
        f4 u0 = p[0], u1 = p[1];
        unsigned int lo = f2fp8(256.0f * u0[0])
                        | (f2fp8(256.0f * u0[1]) << 8)
                        | (f2fp8(256.0f * u0[2]) << 16)
                        | (f2fp8(256.0f * u0[3]) << 24);
        unsigned int hi = f2fp8(256.0f * u1[0])
                        | (f2fp8(256.0f * u1[1]) << 8)
                        | (f2fp8(256.0f * u1[2]) << 16)
                        | (f2fp8(256.0f * u1[3]) << 24);
        unsigned int* dst = (unsigned int*)((char*)ws + kt * 1024 + h * 512 + l * 8);
        dst[0] = lo;
        dst[1] = hi;
    } else if (t < 4096 + KCB) {
        int r = t - 4096;
        const f4* p = (const f4*)(cb + r * DIMS);
        float s = 0.0f;
#pragma unroll
        for (int i = 0; i < DIMS / 4; ++i) {
            f4 v = p[i];
            s += v[0]*v[0] + v[1]*v[1] + v[2]*v[2] + v[3]*v[3];
        }
        ((float*)((char*)ws + 32768))[r] = -128.0f * s;
    }
}

__global__ __launch_bounds__(512, 8) void vq_main(const float* __restrict__ x,
                                                  const float* __restrict__ cb,
                                                  float* __restrict__ out,
                                                  float* __restrict__ ws) {
    __shared__ char lds[34816];   // 32 KiB fp8 codebook + 2 KiB norms

    const int tid  = threadIdx.x;
    const int lane = tid & 63;
    const int wid  = tid >> 6;
    const long wave = (long)blockIdx.x * 8 + wid;
    const long rowbase = wave * 16;               // 16 rows per wave
    const int r15 = lane & 15;
    const int g   = lane >> 4;

    // ---- 2-cohort phase stagger: odd WGs issue their HBM x-loads BEFORE the
    //      staging phase; even WGs after (R11 order). sched_barrier pins it.
    const bool early_x = (blockIdx.x & 1) != 0;
    f4 a0, a1, a2, a3;
    const float* xa = x + (rowbase + r15) * DIMS + g * 8;
    if (early_x) {
        a0 = *(const f4*)(xa);
        a1 = *(const f4*)(xa + 4);
        a2 = *(const f4*)(xa + 32);
        a3 = *(const f4*)(xa + 36);
    }
    __builtin_amdgcn_sched_barrier(0);

    // ---- stage fp8 codebook (32 KiB) + norms (2 KiB) into LDS (linear, coalesced)
    {
        const f4* src = (const f4*)ws;
        f4 s0 = src[tid];
        f4 s1 = src[512 + tid];
        f4 s2 = src[1024 + tid];
        f4 s3 = src[1536 + tid];
        float nv = ((const float*)((const char*)ws + 32768))[tid];
        f4* dst = (f4*)lds;
        dst[tid]        = s0;
        dst[512 + tid]  = s1;
        dst[1024 + tid] = s2;
        dst[1536 + tid] = s3;
        ((float*)(lds + 32768))[tid] = nv;
    }
    __builtin_amdgcn_sched_barrier(0);

    if (!early_x) {
        a0 = *(const f4*)(xa);
        a1 = *(const f4*)(xa + 4);
        a2 = *(const f4*)(xa + 32);
        a3 = *(const f4*)(xa + 36);
    }

    // ---- fp8 A-frags + fp32 row norm
    unsigned long A0, A1;
    float xn0;
    {
        xn0 = a0[0]*a0[0]+a0[1]*a0[1]+a0[2]*a0[2]+a0[3]*a0[3]
            + a1[0]*a1[0]+a1[1]*a1[1]+a1[2]*a1[2]+a1[3]*a1[3]
            + a2[0]*a2[0]+a2[1]*a2[1]+a2[2]*a2[2]+a2[3]*a2[3]
            + a3[0]*a3[0]+a3[1]*a3[1]+a3[2]*a3[2]+a3[3]*a3[3];
        unsigned int t0, t1, t2, t3, t4, t5, t6, t7;
        asm("v_cvt_pk_fp8_f32 %0, %1, %2" : "=v"(t0) : "v"(a0[0]), "v"(a0[1]));
        asm("v_cvt_pk_fp8_f32 %0, %1, %2" : "=v"(t1) : "v"(a0[2]), "v"(a0[3]));
        asm("v_cvt_pk_fp8_f32 %0, %1, %2" : "=v"(t2) : "v"(a1[0]), "v"(a1[1]));
        asm("v_cvt_pk_fp8_f32 %0, %1, %2" : "=v"(t3) : "v"(a1[2]), "v"(a1[3]));
        asm("v_cvt_pk_fp8_f32 %0, %1, %2" : "=v"(t4) : "v"(a2[0]), "v"(a2[1]));
        asm("v_cvt_pk_fp8_f32 %0, %1, %2" : "=v"(t5) : "v"(a2[2]), "v"(a2[3]));
        asm("v_cvt_pk_fp8_f32 %0, %1, %2" : "=v"(t6) : "v"(a3[0]), "v"(a3[1]));
        asm("v_cvt_pk_fp8_f32 %0, %1, %2" : "=v"(t7) : "v"(a3[2]), "v"(a3[3]));
        unsigned int dw0 = (t0 & 0xFFFFu) | (t1 << 16);
        unsigned int dw1 = (t2 & 0xFFFFu) | (t3 << 16);
        unsigned int dw2 = (t4 & 0xFFFFu) | (t5 << 16);
        unsigned int dw3 = (t6 & 0xFFFFu) | (t7 << 16);
        A0 = (unsigned long)dw0 | ((unsigned long)dw1 << 32);
        A1 = (unsigned long)dw2 | ((unsigned long)dw3 << 32);
    }
    xn0 += __shfl_xor(xn0, 16, 64);
    xn0 += __shfl_xor(xn0, 32, 64);

    __syncthreads();   // LDS codebook + norms ready

    // ---- mantissa-packed argmax state (low 9 bits of score carry k)
    float bv0 = -3.4e38f, bv1 = -3.4e38f, bv2 = -3.4e38f, bv3 = -3.4e38f;

    const char*  ldsb = lds;
    const float* ldsn = (const float*)(lds + 32768);
    const int laneoff = lane * 8;

#pragma unroll
    for (int kt = 0; kt < 32; ++kt) {
        unsigned long b0 = *(const unsigned long*)(ldsb + kt * 1024 + laneoff);
        unsigned long b1 = *(const unsigned long*)(ldsb + kt * 1024 + 512 + laneoff);
        float ic = ldsn[kt * 16 + r15];          // conflict-free broadcast read
        f32x4 init = {ic, ic, ic, ic};
        f32x4 q = __builtin_amdgcn_mfma_f32_16x16x32_fp8_fp8((long)A0, (long)b0, init, 0, 0, 0);
        q       = __builtin_amdgcn_mfma_f32_16x16x32_fp8_fp8((long)A1, (long)b1, q,    0, 0, 0);
        const unsigned int kr = (unsigned int)(kt * 16 + r15);
        bv0 = fmaxf(bv0, __uint_as_float((__float_as_uint(q[0]) & 0xFFFFFE00u) | kr));
        bv1 = fmaxf(bv1, __uint_as_float((__float_as_uint(q[1]) & 0xFFFFFE00u) | kr));
        bv2 = fmaxf(bv2, __uint_as_float((__float_as_uint(q[2]) & 0xFFFFFE00u) | kr));
        bv3 = fmaxf(bv3, __uint_as_float((__float_as_uint(q[3]) & 0xFFFFFE00u) | kr));
    }

    // ---- argmax reduce across the 16 entry-lanes of each row-group
#pragma unroll
    for (int st = 0; st < 4; ++st) {
        const int m = 1 << st;
        bv0 = fmaxf(bv0, __shfl_xor(bv0, m, 64));
        bv1 = fmaxf(bv1, __shfl_xor(bv1, m, 64));
        bv2 = fmaxf(bv2, __shfl_xor(bv2, m, 64));
        bv3 = fmaxf(bv3, __shfl_xor(bv3, m, 64));
    }

    // ---- epilogue: pure gather -> store (no x re-read)
    {
        const int orow = lane >> 2;        // 0..15; orow>>2 == g always
        const int cseg = lane & 3;
        const int j2   = orow & 3;
        const int idx = (int)(__float_as_uint(j2 == 0 ? bv0 : j2 == 1 ? bv1 :
                                              j2 == 2 ? bv2 : bv3) & 511u);
        const f4* cq = (const f4*)(cb + (long)idx * DIMS + cseg * 16);
        f4* op = (f4*)(out + (rowbase + orow) * DIMS + cseg * 16);
        op[0] = cq[0]; op[1] = cq[1]; op[2] = cq[2]; op[3] = cq[3];
    }

    // ---- loss from scores: ||q-x||^2 = ||x||^2 - s'/128; per-WAVE partial,
    //      no tail barrier / LDS combine.
    float lsum = 0.0f;
    if (g == (r15 >> 2)) {                 // one lane per row r15
        const int jp = r15 & 3;
        float s0 = jp == 0 ? bv0 : jp == 1 ? bv1 : jp == 2 ? bv2 : bv3;
        s0 = __uint_as_float(__float_as_uint(s0) & 0xFFFFFE00u);
        lsum = xn0 - s0 * 0.0078125f;
    }
#pragma unroll
    for (int s = 0; s < 6; ++s) lsum += __shfl_xor(lsum, 1 << s, 64);
    if (lane == 0) {
        ((float*)((char*)ws + 34816))[wave] = lsum;
    }
}

__global__ __launch_bounds__(256) void vq_final(const float* __restrict__ ws,
                                                float* __restrict__ out) {
    const int t = threadIdx.x;
    const f4* p4 = (const f4*)((const char*)ws + 34816);   // 2048 f4 = 8192 floats
    float s = 0.0f;
#pragma unroll
    for (int i = 0; i < 8; ++i) {
        f4 v = p4[t + 256 * i];
        s += v[0] + v[1] + v[2] + v[3];
    }
#pragma unroll
    for (int st = 0; st < 6; ++st) s += __shfl_xor(s, 1 << st, 64);
    __shared__ float w2[4];
    if ((t & 63) == 0) w2[t >> 6] = s;
    __syncthreads();
    if (t == 0) {
        float total = w2[0] + w2[1] + w2[2] + w2[3];
        out[OUT_Q] = 1.25f * total / 8388608.0f;
    }
}

extern "C" void kernel_launch(void* const* d_in, const int* in_sizes, int n_in,
                              void* d_out, int out_size, void* d_ws, size_t ws_size,
                              hipStream_t stream) {
    const float* x  = (const float*)d_in[0];
    const float* cb = (const float*)d_in[1];
    float* out = (float*)d_out;
    float* ws  = (float*)d_ws;
    vq_prep<<<18, 256, 0, stream>>>(cb, ws);
    vq_main<<<MAIN_WGS, 512, 0, stream>>>(x, cb, out, ws);
    vq_final<<<1, 256, 0, stream>>>(ws, out);
}